// Round 4
// baseline (442.975 us; speedup 1.0000x reference)
//
#include <hip/hip_runtime.h>
#include <hip/hip_bf16.h>
#include <stdint.h>

// GRU cell: B=16384, I=H=1024.
// z = sig(x@Wiz^T + h@Whz^T + bz), r = sig(x@Wir^T + h@Whr^T + br)
// g = tanh(x@Wih^T + bih + r*(h@Whh^T + bhh)); h' = (1-z)g + z h
// bf16 MFMA fused GEMM, 4 accumulator sets (Z,R,GX,GH), K=2048 virtual [x|h].
// R3: 32x32x16 MFMA (2495 TF ceiling vs 2075), full-burst stage + vmcnt(8)
//     1-step-deep prefetch, minimal sched pinning, branch-free convert.
// R4: identical resubmit (R3 hit GPUAcquisitionTimeout, never measured).

#define BM 128
#define BN 128
#define BK 64
#define THREADS 512

typedef __bf16 bf16_t;
typedef __bf16 bf16x8 __attribute__((ext_vector_type(8)));
typedef float f32x16 __attribute__((ext_vector_type(16)));

// workspace layout in bf16 elements
#define XOFF 0
#define HOFF 16777216            // 16384*1024
#define WOFF 33554432            // x + h
#define WSZ  1048576             // 1024*1024

__device__ __forceinline__ void gload16(const void* g, void* l) {
  __builtin_amdgcn_global_load_lds(
      (const __attribute__((address_space(1))) void*)g,
      (__attribute__((address_space(3))) void*)l, 16, 0, 0);
}

__device__ __forceinline__ float fast_sigmoid(float v) {
  return 1.0f / (1.0f + __expf(-v));
}
__device__ __forceinline__ float fast_tanh(float v) {
  float e = __expf(-2.0f * fabsf(v));
  float t = (1.0f - e) / (1.0f + e);
  return v < 0.0f ? -t : t;
}

__device__ __forceinline__ void cvt8(const float* __restrict__ src,
                                     bf16_t* __restrict__ dst) {
  float4 v0 = *(const float4*)src;
  float4 v1 = *(const float4*)(src + 4);
  bf16x8 o;
  o[0] = (__bf16)v0.x; o[1] = (__bf16)v0.y; o[2] = (__bf16)v0.z; o[3] = (__bf16)v0.w;
  o[4] = (__bf16)v1.x; o[5] = (__bf16)v1.y; o[6] = (__bf16)v1.z; o[7] = (__bf16)v1.w;
  *(bf16x8*)dst = o;
}

// fp32 -> bf16: static partition, branch-free inner loops.
// blocks 0..1023: x (2048 u8-units each); 1024..2047: h; 2048..2559: weights.
__global__ __launch_bounds__(256) void convert_bf16(
    const float* __restrict__ x, const float* __restrict__ h,
    const float* __restrict__ wiz, const float* __restrict__ wir,
    const float* __restrict__ wih, const float* __restrict__ whz,
    const float* __restrict__ whr, const float* __restrict__ whh,
    bf16_t* __restrict__ ws)
{
  const int b = blockIdx.x, tid = threadIdx.x;
  if (b < 2048) {
    const float* src = (b < 1024) ? x : h;
    bf16_t* dst = ws + ((b < 1024) ? XOFF : HOFF);
    const long u0 = (long)(b & 1023) * 2048;
    #pragma unroll
    for (int j = 0; j < 8; ++j) {
      long e = (u0 + (long)j * 256 + tid) * 8;
      cvt8(src + e, dst + e);
    }
  } else {
    const int wb = b - 2048;       // 0..511, 1536 units each (6 W * 131072u / 512)
    const long u0 = (long)wb * 1536;
    #pragma unroll
    for (int j = 0; j < 6; ++j) {
      long u = u0 + (long)j * 256 + tid;
      int wi = (int)(u >> 17);
      long off = (u & 131071) * 8;
      const float* wp = (wi == 0) ? wiz : (wi == 1) ? wir : (wi == 2) ? wih
                       : (wi == 3) ? whz : (wi == 4) ? whr : whh;
      cvt8(wp + off, ws + WOFF + (long)wi * WSZ + off);
    }
  }
}

// Fused GRU GEMM. Grid: 1024 blocks (128 m x 8 n), 512 threads, 8 waves (2Mx4N),
// per-wave 64x32 output, 32x32x16 MFMA, 4 gate accumulator sets.
__global__ __launch_bounds__(THREADS, 2) void gru_gemm(
    const bf16_t* __restrict__ ws,
    const float* __restrict__ h_prev,
    const float* __restrict__ biz, const float* __restrict__ bir,
    const float* __restrict__ bih, const float* __restrict__ bhz,
    const float* __restrict__ bhr, const float* __restrict__ bhh,
    float* __restrict__ out)
{
  extern __shared__ char smem[];  // 2 buffers x 64KB: [A 16K][W0 16K][W1 16K][W2 16K]
  const int tid = threadIdx.x;
  const int lane = tid & 63;
  const int wv = tid >> 6;        // wave 0..7
  const int wr = wv >> 2;         // 0..1
  const int wc = wv & 3;          // 0..3
  const int l31 = lane & 31, lhi = lane >> 5;

  // XCD swizzle: each XCD (id%8) owns one n-panel (weights stay L2-resident)
  const int id = blockIdx.x;
  const int swz = (id & 7) * 128 + (id >> 3);
  const int m0 = (swz & 127) * BM;
  const int n0 = (swz >> 7) * BN;

  const bf16_t* xbf  = ws + XOFF;
  const bf16_t* hbf  = ws + HOFF;
  const bf16_t* wizp = ws + WOFF + 0 * WSZ;
  const bf16_t* wirp = ws + WOFF + 1 * WSZ;
  const bf16_t* wihp = ws + WOFF + 2 * WSZ;
  const bf16_t* whzp = ws + WOFF + 3 * WSZ;
  const bf16_t* whrp = ws + WOFF + 4 * WSZ;
  const bf16_t* whhp = ws + WOFF + 5 * WSZ;

  // staging: linear LDS dest (tid*16 per 8KB round); T2 swizzle on global src
  const int rrow = tid >> 3;
  const int ksrc_e = (((tid & 7) ^ (rrow & 7)) << 3);
  const size_t aoff0 = (size_t)(m0 + rrow) * 1024 + ksrc_e;
  const size_t woff0 = (size_t)(n0 + rrow) * 1024 + ksrc_e;
  const int wlds = wv * 1024;

  // swizzled ds_read fragment offsets (32x32x16: row=lane&31, k=ks*16+lhi*8, 8 contig)
  int aoffs[2][4], woffs[4];
  #pragma unroll
  for (int mi = 0; mi < 2; ++mi) {
    int row = wr * 64 + mi * 32 + l31;
    int sw = (row & 7) << 4;
    #pragma unroll
    for (int ks = 0; ks < 4; ++ks)
      aoffs[mi][ks] = row * 128 + ((ks * 32 + lhi * 16) ^ sw);
  }
  {
    int row = wc * 32 + l31;
    int sw = (row & 7) << 4;
    #pragma unroll
    for (int ks = 0; ks < 4; ++ks)
      woffs[ks] = row * 128 + ((ks * 32 + lhi * 16) ^ sw);
  }

  f32x16 accZ[2], accR[2], accGX[2], accGH[2];
  #pragma unroll
  for (int mi = 0; mi < 2; ++mi) {
    accZ[mi] = (f32x16)(0.f); accR[mi] = (f32x16)(0.f);
    accGX[mi] = (f32x16)(0.f); accGH[mi] = (f32x16)(0.f);
  }

  // full-tile stage burst: 8 global_load_lds for tile t into buffer bufp
  auto stage = [&](int bufp, int t) {
    const int kk = (t * BK) & 1023;
    const bool xh = (t < 16);
    const bf16_t* As = xh ? xbf : hbf;
    const bf16_t* W0 = xh ? wizp : whzp;
    const bf16_t* W1 = xh ? wirp : whrp;
    const bf16_t* W2 = xh ? wihp : whhp;
    char* base = smem + bufp * 65536;
    gload16(As + aoff0 + kk,         base + 0     + wlds);
    gload16(As + aoff0 + kk + 65536, base + 8192  + wlds);
    gload16(W0 + woff0 + kk,         base + 16384 + wlds);
    gload16(W0 + woff0 + kk + 65536, base + 24576 + wlds);
    gload16(W1 + woff0 + kk,         base + 32768 + wlds);
    gload16(W1 + woff0 + kk + 65536, base + 40960 + wlds);
    gload16(W2 + woff0 + kk,         base + 49152 + wlds);
    gload16(W2 + woff0 + kk + 65536, base + 57344 + wlds);
  };

  auto kstep = [&](int t, f32x16 (&accG)[2], bool last) {
    const int c = t & 1;
    const char* lb = smem + c * 65536;
    // burst-issue next tile (buf c^1 was freed by the end-barrier of step t-1);
    // counted wait: the 8 just-issued stay in flight a full K-step.
    if (!last) {
      stage(c ^ 1, t + 1);
      asm volatile("s_waitcnt vmcnt(8)" ::: "memory");
    } else {
      asm volatile("s_waitcnt vmcnt(0)" ::: "memory");
    }
    __builtin_amdgcn_s_barrier();       // cross-wave visibility of tile t
    __builtin_amdgcn_sched_barrier(0);  // ds_reads must not hoist above barrier
    bf16x8 a[2][4], bz[4], br[4], bg[4];
    #pragma unroll
    for (int ks = 0; ks < 4; ++ks) {
      a[0][ks] = *(const bf16x8*)(lb + aoffs[0][ks]);
      a[1][ks] = *(const bf16x8*)(lb + aoffs[1][ks]);
      bz[ks]   = *(const bf16x8*)(lb + 16384 + woffs[ks]);
      br[ks]   = *(const bf16x8*)(lb + 32768 + woffs[ks]);
      bg[ks]   = *(const bf16x8*)(lb + 49152 + woffs[ks]);
    }
    __builtin_amdgcn_s_setprio(1);
    #pragma unroll
    for (int ks = 0; ks < 4; ++ks) {
      accZ[0] = __builtin_amdgcn_mfma_f32_32x32x16_bf16(a[0][ks], bz[ks], accZ[0], 0, 0, 0);
      accZ[1] = __builtin_amdgcn_mfma_f32_32x32x16_bf16(a[1][ks], bz[ks], accZ[1], 0, 0, 0);
      accR[0] = __builtin_amdgcn_mfma_f32_32x32x16_bf16(a[0][ks], br[ks], accR[0], 0, 0, 0);
      accR[1] = __builtin_amdgcn_mfma_f32_32x32x16_bf16(a[1][ks], br[ks], accR[1], 0, 0, 0);
      accG[0] = __builtin_amdgcn_mfma_f32_32x32x16_bf16(a[0][ks], bg[ks], accG[0], 0, 0, 0);
      accG[1] = __builtin_amdgcn_mfma_f32_32x32x16_bf16(a[1][ks], bg[ks], accG[1], 0, 0, 0);
    }
    __builtin_amdgcn_s_setprio(0);
    __builtin_amdgcn_s_barrier();       // frees buf c for stage(t+2)
  };

  stage(0, 0);
  #pragma unroll 1
  for (int t = 0; t < 16; ++t) kstep(t, accGX, false);     // x half
  #pragma unroll 1
  for (int t = 16; t < 32; ++t) kstep(t, accGH, t == 31);  // h half

  // ---- epilogue: 32x32 C/D layout: col=lane&31, row=(reg&3)+8*(reg>>2)+4*lhi ----
  const int n_g = n0 + wc * 32 + l31;
  const float bz  = biz[n_g] + bhz[n_g];
  const float br  = bir[n_g] + bhr[n_g];
  const float bgx = bih[n_g];
  const float bgh = bhh[n_g];
  #pragma unroll
  for (int mi = 0; mi < 2; ++mi) {
    #pragma unroll
    for (int reg = 0; reg < 16; ++reg) {
      const int row_in = (reg & 3) + 8 * (reg >> 2) + 4 * lhi;
      const size_t idx = (size_t)(m0 + wr * 64 + mi * 32 + row_in) * 1024 + n_g;
      const float z = fast_sigmoid(accZ[mi][reg] + bz);
      const float r = fast_sigmoid(accR[mi][reg] + br);
      const float g = fast_tanh(accGX[mi][reg] + bgx + r * (accGH[mi][reg] + bgh));
      out[idx] = (1.0f - z) * g + z * h_prev[idx];
    }
  }
}

extern "C" void kernel_launch(void* const* d_in, const int* in_sizes, int n_in,
                              void* d_out, int out_size, void* d_ws, size_t ws_size,
                              hipStream_t stream) {
  (void)in_sizes; (void)n_in; (void)out_size; (void)ws_size;
  const float* x     = (const float*)d_in[0];
  const float* hprev = (const float*)d_in[1];
  const float* Wiz_w = (const float*)d_in[2];
  const float* Wiz_b = (const float*)d_in[3];
  const float* Wir_w = (const float*)d_in[4];
  const float* Wir_b = (const float*)d_in[5];
  const float* Wih_w = (const float*)d_in[6];
  const float* Wih_b = (const float*)d_in[7];
  const float* Whz_w = (const float*)d_in[8];
  const float* Whz_b = (const float*)d_in[9];
  const float* Whr_w = (const float*)d_in[10];
  const float* Whr_b = (const float*)d_in[11];
  const float* Whh_w = (const float*)d_in[12];
  const float* Whh_b = (const float*)d_in[13];
  float* out = (float*)d_out;
  bf16_t* ws = (bf16_t*)d_ws;

  hipFuncSetAttribute(reinterpret_cast<const void*>(gru_gemm),
                      hipFuncAttributeMaxDynamicSharedMemorySize, 131072);

  convert_bf16<<<2560, 256, 0, stream>>>(x, hprev, Wiz_w, Wir_w, Wih_w,
                                         Whz_w, Whr_w, Whh_w, ws);
  gru_gemm<<<1024, THREADS, 131072, stream>>>(ws, hprev, Wiz_b, Wir_b, Wih_b,
                                              Whz_b, Whr_b, Whh_b, out);
}